// Round 1
// baseline (742.066 us; speedup 1.0000x reference)
//
#include <hip/hip_runtime.h>

// Problem constants (fixed in reference setup_inputs)
#define FEAT_C 128
#define NB     4
#define NYv    512
#define NXv    512
#define CG     32                 // channels per gather block
#define NCG    (FEAT_C / CG)      // 4 channel-groups

typedef float vfloat4 __attribute__((ext_vector_type(4)));

// ---------------------------------------------------------------------------
// Kernel 1: scatter voxel ids into idx_map, last-write-wins (max id wins,
// matching numpy fancy-assignment duplicate semantics).
// idx_map pre-initialized to -1 (0xFF memset).
// ---------------------------------------------------------------------------
__global__ void scatter_ids(const int4* __restrict__ coors,
                            int* __restrict__ idx_map, int n) {
    int i = blockIdx.x * blockDim.x + threadIdx.x;
    if (i >= n) return;
    int4 c = coors[i];                       // (b, z, y, x)
    int flat = c.x * (NYv * NXv) + c.z * NXv + c.w;
    atomicMax(&idx_map[flat], i);            // device-scope, cross-XCD safe
}

// ---------------------------------------------------------------------------
// Kernel 2: gather. One block per (b, y, 32-channel group): full 512-px x-row.
//   Rationale vs previous 64-px/128-ch tiles: output writes per block become
//   32 channels x 2 KiB CONTIGUOUS (was 128 x 256 B scattered at 1 MiB
//   stride), restoring DRAM write locality; plain cached stores (not NT) so
//   L2 write-back buffers the streams — the harness's own 2 GiB fill proves
//   this path runs at 6.3 TB/s. No data reuse exists, so skipping NT cannot
//   pollute anything that matters.
// Phase 1: 8 lanes per pixel load 128 B (this block's 32-ch slice of the
//   voxel row) -> exactly one 128 B L2 line, no read amplification; the 4
//   sibling cg-blocks (adjacent blockIdx -> co-dispatched) consume the other
//   quarters of the 512 B row ~concurrently (DRAM row read locality).
// LDS layout XOR-swizzled: channel c of pixel p at word p*32 + (c ^ 4*((p>>2)&7)).
//   Phase-1 b128 writes: 4-aligned (both terms mult of 4); per issue all 32
//   banks uniformly 8-deep (minimum for 1 KiB/wave).
//   Phase-2 b32 reads: bank = (4*it + c_lo) ^ 4*(lane&7) with c_lo=(lane>>4)&3
//   -> 32 distinct banks, 2 lanes/bank = free (m136).
// Writes every output element (implicit zero-fill for empty pixels).
// ---------------------------------------------------------------------------
__global__ __launch_bounds__(512) void gather_bev(
        const float* __restrict__ feat,
        const int* __restrict__ idx_map,
        float* __restrict__ out) {
    __shared__ float tile[NXv * CG];         // 512 px * 32 ch * 4 B = 64 KiB
    __shared__ int sv[NXv];                  // 2 KiB

    const int bid = blockIdx.x;
    const int cg  = bid & (NCG - 1);         // channel group (fastest: siblings co-scheduled)
    const int y   = (bid >> 2) & (NYv - 1);
    const int b   = bid >> 11;
    const int tid = threadIdx.x;

    sv[tid] = idx_map[b * (NYv * NXv) + y * NXv + tid];   // 2 KiB coalesced
    __syncthreads();

    // Phase 1: wave w owns pixels w*64 .. w*64+63. Per iteration one wave
    // covers 8 pixels (8 lanes each); lane reads its 16 B channel-quad.
    const int wave = tid >> 6;
    const int lane = tid & 63;
    const int sub  = lane >> 3;              // pixel within this issue (0..7)
    const int l8   = lane & 7;               // channel quad within 32-ch group
#pragma unroll
    for (int k = 0; k < 8; ++k) {
        const int p = wave * 64 + k * 8 + sub;
        const int v = sv[p];
        vfloat4 f = {0.f, 0.f, 0.f, 0.f};
        if (v >= 0) {
            f = ((const vfloat4*)(feat + (size_t)v * FEAT_C + cg * CG))[l8];
        }
        const int word = p * CG + ((4 * l8) ^ (4 * ((p >> 2) & 7)));
        *(vfloat4*)&tile[word] = f;          // ds_write_b128, aligned
    }
    __syncthreads();

    // Phase 2: 4096 float4 stores (32 c x 128 groups of 4 x), 8 iters/thread.
    // Within a wave-issue: 4 channels x 16 lanes -> 256 B contiguous per
    // channel; across the block each channel's full 2 KiB x-row is written.
    const long plane = (long)NYv * NXv;
    float* out_base = out + ((long)b * FEAT_C + cg * CG) * plane + (long)y * NXv;
#pragma unroll
    for (int it = 0; it < 8; ++it) {
        const int j  = it * 512 + tid;
        const int c  = ((j >> 4) & 3) + 4 * (j >> 9);    // channel in [0,32)
        const int m  = (j & 15) + 16 * ((j >> 6) & 7);   // 4-px group in [0,128)
        const int i0 = m << 2;                           // x offset in row
        const int cs = c ^ (4 * (m & 7));                // swizzled channel slot
        vfloat4 r;
        r.x = tile[(i0 + 0) * CG + cs];
        r.y = tile[(i0 + 1) * CG + cs];
        r.z = tile[(i0 + 2) * CG + cs];
        r.w = tile[(i0 + 3) * CG + cs];
        *(vfloat4*)(out_base + (long)c * plane + i0) = r;   // plain cached store
    }
}

extern "C" void kernel_launch(void* const* d_in, const int* in_sizes, int n_in,
                              void* d_out, int out_size, void* d_ws, size_t ws_size,
                              hipStream_t stream) {
    const float* feat  = (const float*)d_in[0];
    const int*   coors = (const int*)d_in[1];
    const int n = in_sizes[1] / 4;               // N voxels

    int* idx_map = (int*)d_ws;                   // 4 MiB of ws
    const size_t map_bytes = (size_t)NB * NYv * NXv * sizeof(int);

    // ws is re-poisoned to 0xAA before every timed call -> re-init every call.
    // memset 0xFF == int32 -1 (graph-capturable as a memset node).
    (void)hipMemsetAsync(idx_map, 0xFF, map_bytes, stream);

    scatter_ids<<<(n + 255) / 256, 256, 0, stream>>>(
        (const int4*)coors, idx_map, n);

    const int nblocks = NB * NYv * NCG;          // 8192
    gather_bev<<<nblocks, 512, 0, stream>>>(feat, idx_map, (float*)d_out);
}

// Round 2
// 700.372 us; speedup vs baseline: 1.0595x; 1.0595x over previous
//
#include <hip/hip_runtime.h>

// Problem constants (fixed in reference setup_inputs)
#define FEAT_C 128
#define NB     4
#define NYv    512
#define NXv    512
#define PX     256                // x-pixels per gather block (half a row)

typedef float vfloat4 __attribute__((ext_vector_type(4)));

// ---------------------------------------------------------------------------
// Kernel 1: scatter voxel ids into idx_map, last-write-wins (max id wins,
// matching numpy fancy-assignment duplicate semantics).
// idx_map pre-initialized to -1 (0xFF memset).
// ---------------------------------------------------------------------------
__global__ void scatter_ids(const int4* __restrict__ coors,
                            int* __restrict__ idx_map, int n) {
    int i = blockIdx.x * blockDim.x + threadIdx.x;
    if (i >= n) return;
    int4 c = coors[i];                       // (b, z, y, x)
    int flat = c.x * (NYv * NXv) + c.z * NXv + c.w;
    atomicMax(&idx_map[flat], i);            // device-scope, cross-XCD safe
}

// ---------------------------------------------------------------------------
// Kernel 2: gather. One block per (b, y, x-half): 256 px x ALL 128 channels.
// Tile choice rationale (round-0/1 post-mortem): round 0 = 512 B reads but
// 256 B scattered writes; round 1 = 2 KiB writes but 128 B scattered reads;
// each sacrificed one DRAM granule. This tile dominates both:
//   reads : full 512 B voxel row per occupied pixel, one half-wave issue,
//           exactly 4 consecutive 128 B lines — no amplification.
//   writes: 1 KiB contiguous per channel per block (sibling x-half block is
//           co-resident -> ~2 KiB effective runs), NT stores (write-once
//           data, keeps 537 MB stream out of L2).
// 128 KiB LDS + 1 KiB sv -> 1 block/CU, 16 waves: MLP = 16 waves x 8
// outstanding 512 B loads, ample. Phases alternate read-burst/write-burst.
// LDS layout XOR-swizzled: word(p,c) = p*128 + (c ^ 4*((p>>2)&7)).
//   Phase-1 b128 writes: 16 B-aligned, banks uniform 4-deep per half-wave.
//   Phase-2 b32 reads: 2 channels/wave, bank = (c ^ 4*(l&7))&31 -> 16 banks
//   x 4 lanes = 4-way = 1.58x (m136); LDS is ~25x off the critical path.
// Writes every output element (implicit zero-fill for empty pixels).
// ---------------------------------------------------------------------------
__global__ __launch_bounds__(1024) void gather_bev(
        const float* __restrict__ feat,
        const int* __restrict__ idx_map,
        float* __restrict__ out) {
    __shared__ float tile[PX * FEAT_C];      // 256 px * 128 ch * 4 B = 128 KiB
    __shared__ int sv[PX];                   // 1 KiB

    const int bid = blockIdx.x;
    const int xh  = bid & 1;                 // x-half (fastest: siblings co-resident)
    const int y   = (bid >> 1) & (NYv - 1);
    const int b   = bid >> 10;
    const int tid = threadIdx.x;

    if (tid < PX)
        sv[tid] = idx_map[b * (NYv * NXv) + y * NXv + xh * PX + tid];
    __syncthreads();

    // Phase 1: 32 half-waves x 8 pixels each. Per issue a half-wave (32
    // lanes x float4) reads one full 512 B voxel row.
    const int wave = tid >> 6;               // 0..15
    const int lane = tid & 63;
    const int half = lane >> 5;              // 0 or 1
    const int l    = lane & 31;              // float4 slot within a row
    const int hw   = wave * 2 + half;        // half-wave id 0..31
#pragma unroll
    for (int k = 0; k < 8; ++k) {
        const int p = hw * 8 + k;
        const int v = sv[p];
        vfloat4 f = {0.f, 0.f, 0.f, 0.f};
        if (v >= 0) {
            f = ((const vfloat4*)(feat + (size_t)v * FEAT_C))[l];
        }
        const int word = p * FEAT_C + ((4 * l) ^ (4 * ((p >> 2) & 7)));
        *(vfloat4*)&tile[word] = f;          // ds_write_b128, aligned
    }
    __syncthreads();

    // Phase 2: 8192 float4 stores (128 ch x 64 groups of 4 px), 8 iters.
    // Per iteration each half-wave owns ONE channel and stores 512 B
    // contiguous (lanes 0..31 -> x offsets 4l..4l+3 within a 128-px half).
    const long plane = (long)NYv * NXv;
    float* out_base = out + (long)b * FEAT_C * plane + (long)y * NXv + xh * PX;
#pragma unroll
    for (int it = 0; it < 8; ++it) {
        const int h2 = it & 1;               // which 128-px half of the tile
        const int cp = it >> 1;              // channel-quarter 0..3
        const int c  = cp * 32 + wave * 2 + half;   // channel 0..127
        const int i0 = 4 * l + 128 * h2;            // x offset in tile
        const int cs = c ^ (4 * (l & 7));           // swizzled channel slot
        vfloat4 r;
        r.x = tile[(i0 + 0) * FEAT_C + cs];
        r.y = tile[(i0 + 1) * FEAT_C + cs];
        r.z = tile[(i0 + 2) * FEAT_C + cs];
        r.w = tile[(i0 + 3) * FEAT_C + cs];
        __builtin_nontemporal_store(r, (vfloat4*)(out_base + (long)c * plane + i0));
    }
}

extern "C" void kernel_launch(void* const* d_in, const int* in_sizes, int n_in,
                              void* d_out, int out_size, void* d_ws, size_t ws_size,
                              hipStream_t stream) {
    const float* feat  = (const float*)d_in[0];
    const int*   coors = (const int*)d_in[1];
    const int n = in_sizes[1] / 4;               // N voxels

    int* idx_map = (int*)d_ws;                   // 4 MiB of ws
    const size_t map_bytes = (size_t)NB * NYv * NXv * sizeof(int);

    // ws is re-poisoned to 0xAA before every timed call -> re-init every call.
    // memset 0xFF == int32 -1 (graph-capturable as a memset node).
    (void)hipMemsetAsync(idx_map, 0xFF, map_bytes, stream);

    scatter_ids<<<(n + 255) / 256, 256, 0, stream>>>(
        (const int4*)coors, idx_map, n);

    const int nblocks = NB * NYv * (NXv / PX);   // 4096
    gather_bev<<<nblocks, 1024, 0, stream>>>(feat, idx_map, (float*)d_out);
}